// Round 1
// baseline (18861.859 us; speedup 1.0000x reference)
//
#include <hip/hip_runtime.h>
#include <hip/hip_bf16.h>

typedef __hip_bfloat16 bf16;
typedef __attribute__((ext_vector_type(4))) float f32x4;
typedef __attribute__((ext_vector_type(8))) short bf16x8;

#define T_STEPS 512
#define BATCH   32
#define DIM     1024
#define HID     1024
#define GATES   4096
#define NBLK    128   // persistent scan grid (<= 256 CUs -> co-resident)

static __device__ __forceinline__ float sigmf(float x) {
    return 1.0f / (1.0f + __expf(-x));
}
// overflow-safe tanh via exp: +/-inf exp -> correct +/-1, no NaN
static __device__ __forceinline__ float tanhfast(float x) {
    return 1.0f - 2.0f / (__expf(2.0f * x) + 1.0f);
}

// ---------------------------------------------------------------- prep ----
__global__ void prep_kernel(const float* __restrict__ input,
                            const float* __restrict__ Wx,
                            const float* __restrict__ Wh,
                            const float* __restrict__ h0,
                            bf16* __restrict__ input_b,
                            bf16* __restrict__ Wx_b,
                            bf16* __restrict__ Wh_b,
                            bf16* __restrict__ h_b,
                            unsigned* __restrict__ bar) {
    const size_t NIN = (size_t)T_STEPS * BATCH * DIM;   // 16,777,216
    const size_t NW  = (size_t)GATES * DIM;             // 4,194,304
    const size_t NH  = (size_t)BATCH * HID;             // 32,768
    const size_t stride = (size_t)gridDim.x * blockDim.x;
    const size_t t0 = (size_t)blockIdx.x * blockDim.x + threadIdx.x;
    for (size_t i = t0; i < NIN; i += stride) input_b[i] = __float2bfloat16(input[i]);
    for (size_t i = t0; i < NW;  i += stride) Wx_b[i]    = __float2bfloat16(Wx[i]);
    for (size_t i = t0; i < NW;  i += stride) Wh_b[i]    = __float2bfloat16(Wh[i]);
    for (size_t i = t0; i < NH;  i += stride) h_b[i]     = __float2bfloat16(h0[i]);
    if (t0 == 0) bar[0] = 0u;
}

// ------------------------------------------------- big GEMM: gates_x -----
// C[M=16384][N=4096] = A[M][K=1024] @ W[N][K]^T   (bf16 in, bf16 out, fp32 acc)
__global__ __launch_bounds__(256) void gemm_input(const bf16* __restrict__ A,
                                                  const bf16* __restrict__ W,
                                                  bf16* __restrict__ C) {
    const int bn = blockIdx.x & 31;    // 32 N-tiles of 128
    const int bm = blockIdx.x >> 5;    // 128 M-tiles of 128
    const int lane = threadIdx.x & 63;
    const int w = threadIdx.x >> 6;                 // wave 0..3
    const int wm = (w >> 1) * 64, wn = (w & 1) * 64;
    const int lr = lane & 15;
    const int ko = (lane >> 4) * 8;

    const bf16* Abase = A + (size_t)(bm * 128 + wm + lr) * DIM + ko;
    const bf16* Wbase = W + (size_t)(bn * 128 + wn + lr) * DIM + ko;

    f32x4 acc[4][4] = {};
    for (int k = 0; k < DIM; k += 32) {
        bf16x8 af[4], bw[4];
#pragma unroll
        for (int m = 0; m < 4; ++m)
            af[m] = *(const bf16x8*)(Abase + (size_t)m * 16 * DIM + k);
#pragma unroll
        for (int n = 0; n < 4; ++n)
            bw[n] = *(const bf16x8*)(Wbase + (size_t)n * 16 * DIM + k);
#pragma unroll
        for (int m = 0; m < 4; ++m)
#pragma unroll
            for (int n = 0; n < 4; ++n)
                acc[m][n] = __builtin_amdgcn_mfma_f32_16x16x32_bf16(af[m], bw[n], acc[m][n], 0, 0, 0);
    }
    const int cr = (lane >> 4) * 4;
#pragma unroll
    for (int m = 0; m < 4; ++m)
#pragma unroll
        for (int n = 0; n < 4; ++n)
#pragma unroll
            for (int r = 0; r < 4; ++r) {
                int row = bm * 128 + wm + m * 16 + cr + r;
                int col = bn * 128 + wn + n * 16 + lr;
                C[(size_t)row * GATES + col] = __float2bfloat16(acc[m][n][r]);
            }
}

// ------------------------------------------------------- grid barrier ----
static __device__ __forceinline__ void gbar(unsigned* bar, unsigned target) {
    __syncthreads();
    if (threadIdx.x == 0) {
        __threadfence();  // release: publish this block's stores device-wide
        __hip_atomic_fetch_add(bar, 1u, __ATOMIC_ACQ_REL, __HIP_MEMORY_SCOPE_AGENT);
        while (__hip_atomic_load(bar, __ATOMIC_ACQUIRE, __HIP_MEMORY_SCOPE_AGENT) < target) {
            __builtin_amdgcn_s_sleep(1);
        }
        __threadfence();  // acquire: invalidate stale cached lines
    }
    __syncthreads();
}

static __device__ __forceinline__ void block_reduce2(float& s, float& s2,
                                                     float (*red)[4], int lane, int w) {
#pragma unroll
    for (int off = 32; off > 0; off >>= 1) {
        s  += __shfl_down(s, off, 64);
        s2 += __shfl_down(s2, off, 64);
    }
    if (lane == 0) { red[0][w] = s; red[1][w] = s2; }
    __syncthreads();
    s  = red[0][0] + red[0][1] + red[0][2] + red[0][3];
    s2 = red[1][0] + red[1][1] + red[1][2] + red[1][3];
    __syncthreads();  // red is reused by the next reduction
}

// -------------------------------------------------- persistent scan ------
__global__ __launch_bounds__(256) void scan_kernel(
    const bf16* __restrict__ gx,        // [T][B][4096] bf16 (precomputed x-projection)
    const bf16* __restrict__ Wh_b,      // [4096][1024] bf16
    const float* __restrict__ c0,       // [B][H]
    const float* __restrict__ gn_g, const float* __restrict__ gn_b,
    const float* __restrict__ cn_g, const float* __restrict__ cn_b,
    bf16* __restrict__ h_b,             // [B][H] recurrent state (bf16)
    float* __restrict__ gates_pre,      // [B][4096] scratch
    float* __restrict__ out,            // [T][B][H]
    float* __restrict__ h_final,        // [B][H]
    float* __restrict__ c_final,        // [B][H]
    unsigned* __restrict__ bar) {

    const int tid  = threadIdx.x;
    const int lane = tid & 63;
    const int wid  = (blockIdx.x << 2) + (tid >> 6);   // 0..511: one 16x16 tile each
    const int ni = wid & 255, mi = wid >> 8;
    const int lr = lane & 15;
    const int ko = (lane >> 4) * 8;
    const int cr = (lane >> 4) * 4;

    const bf16* hbase = h_b + (size_t)(mi * 16 + lr) * HID + ko;
    const bf16* wbase = Wh_b + (size_t)(ni * 16 + lr) * HID + ko;
    const int gcol = ni * 16 + lr;
    const int brow = mi * 16 + cr;

    // phase-2 per-batch state: c lives entirely in registers of block b (<32)
    const int b = blockIdx.x;
    float creg[4];
    if (b < BATCH) {
#pragma unroll
        for (int q = 0; q < 4; ++q) creg[q] = c0[b * HID + q * 256 + tid];
    }
    __shared__ float red[2][4];
    unsigned target = 0;

    for (int t = 0; t < T_STEPS; ++t) {
        // ---- phase 1: gates_pre = gx[t] + h @ Wh^T (512 waves, 1 tile each) ----
        {
            f32x4 acc = {0.f, 0.f, 0.f, 0.f};
#pragma unroll 8
            for (int kk = 0; kk < 32; ++kk) {
                bf16x8 a  = *(const bf16x8*)(hbase + kk * 32);
                bf16x8 bb = *(const bf16x8*)(wbase + kk * 32);
                acc = __builtin_amdgcn_mfma_f32_16x16x32_bf16(a, bb, acc, 0, 0, 0);
            }
            const bf16* gxp = gx + ((size_t)t * BATCH + brow) * GATES + gcol;
#pragma unroll
            for (int r = 0; r < 4; ++r)
                gates_pre[(brow + r) * GATES + gcol] = acc[r] + __bfloat162float(gxp[(size_t)r * GATES]);
        }
        target += NBLK;
        gbar(bar, target);

        // ---- phase 2: per-batch LN + LSTM cell (32 blocks, 1 batch row each) ----
        if (b < BATCH) {
            float g0[4], g1[4], g2[4], g3[4];
            float s = 0.f, s2 = 0.f;
#pragma unroll
            for (int q = 0; q < 4; ++q) {
                int j = q * 256 + tid;
                g0[q] = gates_pre[b * GATES + j];
                g1[q] = gates_pre[b * GATES + HID + j];
                g2[q] = gates_pre[b * GATES + 2 * HID + j];
                g3[q] = gates_pre[b * GATES + 3 * HID + j];
                s  += g0[q] + g1[q] + g2[q] + g3[q];
                s2 += g0[q] * g0[q] + g1[q] * g1[q] + g2[q] * g2[q] + g3[q] * g3[q];
            }
            block_reduce2(s, s2, red, lane, tid >> 6);
            const float mu   = s * (1.0f / GATES);
            const float rstd = rsqrtf(s2 * (1.0f / GATES) - mu * mu + 1e-5f);

            float ov[4], cn_[4];
            float cs = 0.f, cs2 = 0.f;
#pragma unroll
            for (int q = 0; q < 4; ++q) {
                int j = q * 256 + tid;
                float iv = sigmf(   (g0[q] - mu) * rstd * gn_g[j]           + gn_b[j]);
                float fv = sigmf(   (g1[q] - mu) * rstd * gn_g[HID + j]     + gn_b[HID + j]);
                float gv = tanhfast((g2[q] - mu) * rstd * gn_g[2 * HID + j] + gn_b[2 * HID + j]);
                ov[q] =             (g3[q] - mu) * rstd * gn_g[3 * HID + j] + gn_b[3 * HID + j];
                float cnew = fv * creg[q] + iv * gv;
                cn_[q] = cnew;
                cs += cnew; cs2 += cnew * cnew;
            }
            block_reduce2(cs, cs2, red, lane, tid >> 6);
            const float mu2   = cs * (1.0f / HID);
            const float rstd2 = rsqrtf(cs2 * (1.0f / HID) - mu2 * mu2 + 1e-5f);

            float* orow = out + ((size_t)t * BATCH + b) * HID;
#pragma unroll
            for (int q = 0; q < 4; ++q) {
                int j = q * 256 + tid;
                float cn = (cn_[q] - mu2) * rstd2 * cn_g[j] + cn_b[j];
                creg[q] = cn;
                float hv = sigmf(ov[q]) * tanhfast(cn);
                orow[j] = hv;
                h_b[b * HID + j] = __float2bfloat16(hv);
                if (t == T_STEPS - 1) {
                    h_final[b * HID + j] = hv;
                    c_final[b * HID + j] = cn;
                }
            }
        }
        target += NBLK;
        gbar(bar, target);
    }
}

// ----------------------------------------------------------- launcher ----
extern "C" void kernel_launch(void* const* d_in, const int* in_sizes, int n_in,
                              void* d_out, int out_size, void* d_ws, size_t ws_size,
                              hipStream_t stream) {
    const float* input = (const float*)d_in[0];
    const float* h0    = (const float*)d_in[1];
    const float* c0    = (const float*)d_in[2];
    const float* Wx    = (const float*)d_in[3];
    const float* Wh    = (const float*)d_in[4];
    const float* gn_g  = (const float*)d_in[5];
    const float* gn_b  = (const float*)d_in[6];
    const float* cn_g  = (const float*)d_in[7];
    const float* cn_b  = (const float*)d_in[8];

    char* ws = (char*)d_ws;
    size_t off = 0;
    auto alloc = [&](size_t bytes) -> char* {
        char* p = ws + off;
        off += (bytes + 255) & ~(size_t)255;
        return p;
    };
    bf16*     input_b   = (bf16*)    alloc((size_t)T_STEPS * BATCH * DIM * 2);   // 32 MB
    bf16*     Wx_b      = (bf16*)    alloc((size_t)GATES * DIM * 2);             // 8 MB
    bf16*     Wh_b      = (bf16*)    alloc((size_t)GATES * DIM * 2);             // 8 MB
    bf16*     gates_x   = (bf16*)    alloc((size_t)T_STEPS * BATCH * GATES * 2); // 128 MB
    float*    gates_pre = (float*)   alloc((size_t)BATCH * GATES * 4);           // 512 KB
    bf16*     h_b       = (bf16*)    alloc((size_t)BATCH * HID * 2);             // 64 KB
    unsigned* bar       = (unsigned*)alloc(256);

    float* outp    = (float*)d_out;
    float* h_final = outp + (size_t)T_STEPS * BATCH * HID;
    float* c_final = h_final + (size_t)BATCH * HID;

    hipLaunchKernelGGL(prep_kernel, dim3(2048), dim3(256), 0, stream,
                       input, Wx, Wh, h0, input_b, Wx_b, Wh_b, h_b, bar);

    hipLaunchKernelGGL(gemm_input, dim3(4096), dim3(256), 0, stream,
                       input_b, Wx_b, gates_x);

    hipLaunchKernelGGL(scan_kernel, dim3(NBLK), dim3(256), 0, stream,
                       gates_x, Wh_b, c0, gn_g, gn_b, cn_g, cn_b,
                       h_b, gates_pre, outp, h_final, c_final, bar);
}

// Round 3
// 11641.066 us; speedup vs baseline: 1.6203x; 1.6203x over previous
//
#include <hip/hip_runtime.h>
#include <hip/hip_bf16.h>

typedef __hip_bfloat16 bf16;
typedef __attribute__((ext_vector_type(4))) float f32x4;
typedef __attribute__((ext_vector_type(8))) short bf16x8;
typedef unsigned long long u64;

#define T_STEPS 512
#define BATCH   32
#define DIM     1024
#define HID     1024
#define GATES   4096
#define NBLK    128   // persistent scan grid (1 block/CU on 128 of 256 CUs)

static __device__ __forceinline__ float sigmf(float x) {
    return 1.0f / (1.0f + __expf(-x));
}
// overflow-safe tanh via exp: +/-inf exp -> correct +/-1, no NaN
static __device__ __forceinline__ float tanhfast(float x) {
    return 1.0f - 2.0f / (__expf(2.0f * x) + 1.0f);
}

// coherent (LLC-level) access helpers: relaxed agent atomics emit sc-qualified
// device-scope ops -- NO cache-wide fences, L1/L2 stay warm for read-only data.
static __device__ __forceinline__ u64 ldc_u64(const u64* p) {
    return __hip_atomic_load((u64*)p, __ATOMIC_RELAXED, __HIP_MEMORY_SCOPE_AGENT);
}
static __device__ __forceinline__ void stc_u64(u64* p, u64 v) {
    __hip_atomic_store(p, v, __ATOMIC_RELAXED, __HIP_MEMORY_SCOPE_AGENT);
}
static __device__ __forceinline__ void stc_f32(float* p, float v) {
    __hip_atomic_store(p, v, __ATOMIC_RELAXED, __HIP_MEMORY_SCOPE_AGENT);
}

// ---------------------------------------------------------------- prep ----
__global__ void prep_kernel(const float* __restrict__ input,
                            const float* __restrict__ Wx,
                            const float* __restrict__ Wh,
                            const float* __restrict__ h0,
                            bf16* __restrict__ input_b,
                            bf16* __restrict__ Wx_b,
                            bf16* __restrict__ Wh_b,
                            bf16* __restrict__ h_b,
                            unsigned* __restrict__ bar) {
    const size_t NIN = (size_t)T_STEPS * BATCH * DIM;
    const size_t NW  = (size_t)GATES * DIM;
    const size_t NH  = (size_t)BATCH * HID;
    const size_t stride = (size_t)gridDim.x * blockDim.x;
    const size_t t0 = (size_t)blockIdx.x * blockDim.x + threadIdx.x;
    for (size_t i = t0; i < NIN; i += stride) input_b[i] = __float2bfloat16(input[i]);
    for (size_t i = t0; i < NW;  i += stride) Wx_b[i]    = __float2bfloat16(Wx[i]);
    for (size_t i = t0; i < NW;  i += stride) Wh_b[i]    = __float2bfloat16(Wh[i]);
    for (size_t i = t0; i < NH;  i += stride) h_b[i]     = __float2bfloat16(h0[i]);
    if (t0 == 0) bar[0] = 0u;
}

// ------------------------------------------------- big GEMM: gates_x -----
// C[M=16384][N=4096] = A[M][K=1024] @ W[N][K]^T   (bf16 in, bf16 out, fp32 acc)
__global__ __launch_bounds__(256) void gemm_input(const bf16* __restrict__ A,
                                                  const bf16* __restrict__ W,
                                                  bf16* __restrict__ C) {
    const int bn = blockIdx.x & 31;
    const int bm = blockIdx.x >> 5;
    const int lane = threadIdx.x & 63;
    const int w = threadIdx.x >> 6;
    const int wm = (w >> 1) * 64, wn = (w & 1) * 64;
    const int lr = lane & 15;
    const int ko = (lane >> 4) * 8;

    const bf16* Abase = A + (size_t)(bm * 128 + wm + lr) * DIM + ko;
    const bf16* Wbase = W + (size_t)(bn * 128 + wn + lr) * DIM + ko;

    f32x4 acc[4][4] = {};
    for (int k = 0; k < DIM; k += 32) {
        bf16x8 af[4], bw[4];
#pragma unroll
        for (int m = 0; m < 4; ++m)
            af[m] = *(const bf16x8*)(Abase + (size_t)m * 16 * DIM + k);
#pragma unroll
        for (int n = 0; n < 4; ++n)
            bw[n] = *(const bf16x8*)(Wbase + (size_t)n * 16 * DIM + k);
#pragma unroll
        for (int m = 0; m < 4; ++m)
#pragma unroll
            for (int n = 0; n < 4; ++n)
                acc[m][n] = __builtin_amdgcn_mfma_f32_16x16x32_bf16(af[m], bw[n], acc[m][n], 0, 0, 0);
    }
    const int cr = (lane >> 4) * 4;
#pragma unroll
    for (int m = 0; m < 4; ++m)
#pragma unroll
        for (int n = 0; n < 4; ++n)
#pragma unroll
            for (int r = 0; r < 4; ++r) {
                int row = bm * 128 + wm + m * 16 + cr + r;
                int col = bn * 128 + wn + n * 16 + lr;
                C[(size_t)row * GATES + col] = __float2bfloat16(acc[m][n][r]);
            }
}

// --------------------------------------------- fence-free grid barrier ----
// Release: __syncthreads drains each wave's vmcnt(0) (all coherent stores
// acked at LLC) before any wave arrives. Arrival/spin: relaxed agent atomics
// (LLC-coherent, NO buffer_wbl2/buffer_inv emitted). Consumers read shared
// data with coherent loads, so no L2 invalidate is ever needed.
static __device__ __forceinline__ void gbar(unsigned* bar, unsigned target) {
    __syncthreads();
    if (threadIdx.x == 0) {
        asm volatile("s_waitcnt vmcnt(0)" ::: "memory");
        __hip_atomic_fetch_add(bar, 1u, __ATOMIC_RELAXED, __HIP_MEMORY_SCOPE_AGENT);
        while (__hip_atomic_load(bar, __ATOMIC_RELAXED, __HIP_MEMORY_SCOPE_AGENT) < target) {}
    }
    __syncthreads();
}

static __device__ __forceinline__ void block_reduce2(float& s, float& s2,
                                                     float (*red)[4], int lane, int w) {
#pragma unroll
    for (int off = 32; off > 0; off >>= 1) {
        s  += __shfl_down(s, off, 64);
        s2 += __shfl_down(s2, off, 64);
    }
    if (lane == 0) { red[0][w] = s; red[1][w] = s2; }
    __syncthreads();
    s  = red[0][0] + red[0][1] + red[0][2] + red[0][3];
    s2 = red[1][0] + red[1][1] + red[1][2] + red[1][3];
    __syncthreads();
}

// -------------------------------------------------- persistent scan ------
// 128 blocks: block = (colg, mi). Phase 1: gates[b= mi*16..+16][colg*64..+64]
// via MFMA (h staged in swizzled LDS). Phase 2: block b<32 owns batch b.
__global__ __launch_bounds__(256) void scan_kernel(
    const bf16* __restrict__ gx,        // [T][B][4096] bf16
    const bf16* __restrict__ Wh_b,      // [4096][1024] bf16 (L2-resident)
    const float* __restrict__ c0,
    const float* __restrict__ gn_g, const float* __restrict__ gn_b,
    const float* __restrict__ cn_g, const float* __restrict__ cn_b,
    bf16* __restrict__ h_b,             // [B][H] recurrent state (coherent)
    float* __restrict__ gates_pre,      // [B][4096] scratch (coherent)
    float* __restrict__ out,
    float* __restrict__ h_final,
    float* __restrict__ c_final,
    unsigned* __restrict__ bar) {

    const int tid  = threadIdx.x;
    const int lane = tid & 63;
    const int w    = tid >> 6;
    const int mi   = blockIdx.x & 1;     // batch half: rows mi*16..+16
    const int colg = blockIdx.x >> 1;    // 0..63: gate cols [colg*64, +64)
    const int ni   = colg * 4 + w;       // this wave's 16-col tile
    const int lr   = lane & 15;
    const int ko   = (lane >> 4) * 8;
    const int cr   = (lane >> 4) * 4;
    const int gcol = ni * 16 + lr;
    const int brow = mi * 16 + cr;

    __shared__ __align__(16) char hsm[16 * 2048];   // 16 rows x 1024 bf16, XOR-swizzled
    __shared__ float red[2][4];

    const bf16* wbase = Wh_b + (size_t)(ni * 16 + lr) * HID + ko;   // normal cached
    const int arow = lr * 2048;
    const int axor = (lr & 7) << 4;

    // phase-2 state: block b (<32) owns batch b; c in registers, elems 4*tid+q
    const int b = blockIdx.x;
    float creg[4];
    if (b < BATCH) {
#pragma unroll
        for (int q = 0; q < 4; ++q) creg[q] = c0[b * HID + 4 * tid + q];
    }
    unsigned tgt = 0;

    for (int t = 0; t < T_STEPS; ++t) {
        // ---- phase 1a: stage h rows [mi*16, +16) into swizzled LDS ----
        // h row = 1024 bf16 = 2048 B = 256 u64.  (round-2 bug: used >>7/&127,
        // i.e. 128-u64 rows -> OOB LDS writes + wrong fragments. Fixed.)
        {
            const u64* hsrc = (const u64*)(h_b + (size_t)mi * 16 * HID);
#pragma unroll
            for (int u = 0; u < 16; ++u) {
                int i = u * 256 + tid;           // u64 granule 0..4095
                int row = i >> 8;                // 256 u64 per row
                int off8 = (i & 255) << 3;       // byte 0..2047 within row
                u64 v = ldc_u64(hsrc + i);
                *(u64*)(hsm + row * 2048 + (off8 ^ ((row & 7) << 4))) = v;
            }
        }
        __syncthreads();

        // ---- phase 1b: 16x16 tile of h @ Wh^T, add gx, publish gates ----
        {
            f32x4 acc = {0.f, 0.f, 0.f, 0.f};
#pragma unroll 8
            for (int kk = 0; kk < 32; ++kk) {
                bf16x8 a = *(const bf16x8*)(hsm + arow + ((kk * 64 + ko * 2) ^ axor));
                bf16x8 bb = *(const bf16x8*)(wbase + kk * 32);
                acc = __builtin_amdgcn_mfma_f32_16x16x32_bf16(a, bb, acc, 0, 0, 0);
            }
            const bf16* gxp = gx + ((size_t)t * BATCH + brow) * GATES + gcol;
            float* gp = gates_pre + (size_t)brow * GATES + gcol;
#pragma unroll
            for (int r = 0; r < 4; ++r)
                stc_f32(gp + (size_t)r * GATES,
                        acc[r] + __bfloat162float(gxp[(size_t)r * GATES]));
        }
        tgt += NBLK;
        gbar(bar, tgt);

        // ---- phase 2: batch-owner blocks do LN + LSTM cell ----
        if (b < BATCH) {
            const u64* grow = (const u64*)(gates_pre + (size_t)b * GATES);
            float g[4][4];
            float s = 0.f, s2 = 0.f;
#pragma unroll
            for (int gq = 0; gq < 4; ++gq) {
                union { u64 u; float f[2]; } v0, v1;
                v0.u = ldc_u64(grow + gq * 512 + 2 * tid);
                v1.u = ldc_u64(grow + gq * 512 + 2 * tid + 1);
                g[gq][0] = v0.f[0]; g[gq][1] = v0.f[1];
                g[gq][2] = v1.f[0]; g[gq][3] = v1.f[1];
#pragma unroll
                for (int q = 0; q < 4; ++q) { s += g[gq][q]; s2 += g[gq][q] * g[gq][q]; }
            }
            block_reduce2(s, s2, red, lane, w);
            const float mu   = s * (1.0f / GATES);
            const float rstd = rsqrtf(s2 * (1.0f / GATES) - mu * mu + 1e-5f);

            float ov[4], cn_[4];
            float cs = 0.f, cs2 = 0.f;
#pragma unroll
            for (int q = 0; q < 4; ++q) {
                int j = 4 * tid + q;
                float iv = sigmf(   (g[0][q] - mu) * rstd * gn_g[j]            + gn_b[j]);
                float fv = sigmf(   (g[1][q] - mu) * rstd * gn_g[HID + j]      + gn_b[HID + j]);
                float gv = tanhfast((g[2][q] - mu) * rstd * gn_g[2 * HID + j]  + gn_b[2 * HID + j]);
                ov[q] =             (g[3][q] - mu) * rstd * gn_g[3 * HID + j]  + gn_b[3 * HID + j];
                float cnew = fv * creg[q] + iv * gv;
                cn_[q] = cnew;
                cs += cnew; cs2 += cnew * cnew;
            }
            block_reduce2(cs, cs2, red, lane, w);
            const float mu2   = cs * (1.0f / HID);
            const float rstd2 = rsqrtf(cs2 * (1.0f / HID) - mu2 * mu2 + 1e-5f);

            float* orow = out + ((size_t)t * BATCH + b) * HID + 4 * tid;
            union { u64 u; unsigned short h[4]; } hpack;
#pragma unroll
            for (int q = 0; q < 4; ++q) {
                int j = 4 * tid + q;
                float cn = (cn_[q] - mu2) * rstd2 * cn_g[j] + cn_b[j];
                creg[q] = cn;
                float hv = sigmf(ov[q]) * tanhfast(cn);
                orow[q] = hv;                                  // normal store
                hpack.h[q] = __bfloat16_as_ushort(__float2bfloat16(hv));
                if (t == T_STEPS - 1) {
                    h_final[b * HID + j] = hv;
                    c_final[b * HID + j] = cn;
                }
            }
            stc_u64((u64*)(h_b + (size_t)b * HID + 4 * tid), hpack.u);  // coherent publish
        }
        tgt += NBLK;
        gbar(bar, tgt);
    }
}

// ----------------------------------------------------------- launcher ----
extern "C" void kernel_launch(void* const* d_in, const int* in_sizes, int n_in,
                              void* d_out, int out_size, void* d_ws, size_t ws_size,
                              hipStream_t stream) {
    const float* input = (const float*)d_in[0];
    const float* h0    = (const float*)d_in[1];
    const float* c0    = (const float*)d_in[2];
    const float* Wx    = (const float*)d_in[3];
    const float* Wh    = (const float*)d_in[4];
    const float* gn_g  = (const float*)d_in[5];
    const float* gn_b  = (const float*)d_in[6];
    const float* cn_g  = (const float*)d_in[7];
    const float* cn_b  = (const float*)d_in[8];

    char* ws = (char*)d_ws;
    size_t off = 0;
    auto alloc = [&](size_t bytes) -> char* {
        char* p = ws + off;
        off += (bytes + 255) & ~(size_t)255;
        return p;
    };
    bf16*     input_b   = (bf16*)    alloc((size_t)T_STEPS * BATCH * DIM * 2);
    bf16*     Wx_b      = (bf16*)    alloc((size_t)GATES * DIM * 2);
    bf16*     Wh_b      = (bf16*)    alloc((size_t)GATES * DIM * 2);
    bf16*     gates_x   = (bf16*)    alloc((size_t)T_STEPS * BATCH * GATES * 2);
    float*    gates_pre = (float*)   alloc((size_t)BATCH * GATES * 4);
    bf16*     h_b       = (bf16*)    alloc((size_t)BATCH * HID * 2);
    unsigned* bar       = (unsigned*)alloc(256);

    float* outp    = (float*)d_out;
    float* h_final = outp + (size_t)T_STEPS * BATCH * HID;
    float* c_final = h_final + (size_t)BATCH * HID;

    hipLaunchKernelGGL(prep_kernel, dim3(2048), dim3(256), 0, stream,
                       input, Wx, Wh, h0, input_b, Wx_b, Wh_b, h_b, bar);

    hipLaunchKernelGGL(gemm_input, dim3(4096), dim3(256), 0, stream,
                       input_b, Wx_b, gates_x);

    hipLaunchKernelGGL(scan_kernel, dim3(NBLK), dim3(256), 0, stream,
                       gates_x, Wh_b, c0, gn_g, gn_b, cn_g, cn_b,
                       h_b, gates_pre, outp, h_final, c_final, bar);
}

// Round 4
// 9053.490 us; speedup vs baseline: 2.0834x; 1.2858x over previous
//
#include <hip/hip_runtime.h>
#include <hip/hip_bf16.h>

typedef __hip_bfloat16 bf16;
typedef __attribute__((ext_vector_type(4))) float f32x4;
typedef __attribute__((ext_vector_type(8))) short bf16x8;
typedef unsigned long long u64;
typedef unsigned short u16;

#define T_STEPS 512
#define BATCH   32
#define DIM     1024
#define HID     1024
#define GATES   4096
#define NBLK    128   // persistent scan grid; two independent 64-block halves
#define HBLK    64

static __device__ __forceinline__ float sigmf(float x) {
    return 1.0f / (1.0f + __expf(-x));
}
// overflow-safe tanh via exp: +/-inf exp -> correct +/-1, no NaN
static __device__ __forceinline__ float tanhfast(float x) {
    return 1.0f - 2.0f / (__expf(2.0f * x) + 1.0f);
}

// coherent (LLC-level) access helpers: relaxed agent atomics emit sc-qualified
// device-scope ops -- NO cache-wide fences, L1/L2 stay warm for read-only data.
static __device__ __forceinline__ u64 ldc_u64(const u64* p) {
    return __hip_atomic_load((u64*)p, __ATOMIC_RELAXED, __HIP_MEMORY_SCOPE_AGENT);
}
static __device__ __forceinline__ void stc_u64(u64* p, u64 v) {
    __hip_atomic_store(p, v, __ATOMIC_RELAXED, __HIP_MEMORY_SCOPE_AGENT);
}
static __device__ __forceinline__ void stc_f32(float* p, float v) {
    __hip_atomic_store(p, v, __ATOMIC_RELAXED, __HIP_MEMORY_SCOPE_AGENT);
}

// ---------------------------------------------------------------- prep ----
__global__ void prep_kernel(const float* __restrict__ input,
                            const float* __restrict__ Wx,
                            const float* __restrict__ Wh,
                            const float* __restrict__ h0,
                            bf16* __restrict__ input_b,
                            bf16* __restrict__ Wx_b,
                            bf16* __restrict__ Wh_b,
                            bf16* __restrict__ h_b,
                            unsigned* __restrict__ bar) {
    const size_t NIN = (size_t)T_STEPS * BATCH * DIM;
    const size_t NW  = (size_t)GATES * DIM;
    const size_t NH  = (size_t)BATCH * HID;
    const size_t stride = (size_t)gridDim.x * blockDim.x;
    const size_t t0 = (size_t)blockIdx.x * blockDim.x + threadIdx.x;
    for (size_t i = t0; i < NIN; i += stride) input_b[i] = __float2bfloat16(input[i]);
    for (size_t i = t0; i < NW;  i += stride) Wx_b[i]    = __float2bfloat16(Wx[i]);
    for (size_t i = t0; i < NW;  i += stride) Wh_b[i]    = __float2bfloat16(Wh[i]);
    for (size_t i = t0; i < NH;  i += stride) h_b[i]     = __float2bfloat16(h0[i]);
    if (t0 < 2048) bar[t0] = 0u;   // 2 halves x 1024 dwords of barrier state
}

// ------------------------------------------------- big GEMM: gates_x -----
// C[M=16384][N=4096] = A[M][K=1024] @ W[N][K]^T   (bf16 in, bf16 out, fp32 acc)
__global__ __launch_bounds__(256) void gemm_input(const bf16* __restrict__ A,
                                                  const bf16* __restrict__ W,
                                                  bf16* __restrict__ C) {
    const int bn = blockIdx.x & 31;
    const int bm = blockIdx.x >> 5;
    const int lane = threadIdx.x & 63;
    const int w = threadIdx.x >> 6;
    const int wm = (w >> 1) * 64, wn = (w & 1) * 64;
    const int lr = lane & 15;
    const int ko = (lane >> 4) * 8;

    const bf16* Abase = A + (size_t)(bm * 128 + wm + lr) * DIM + ko;
    const bf16* Wbase = W + (size_t)(bn * 128 + wn + lr) * DIM + ko;

    f32x4 acc[4][4] = {};
    for (int k = 0; k < DIM; k += 32) {
        bf16x8 af[4], bw[4];
#pragma unroll
        for (int m = 0; m < 4; ++m)
            af[m] = *(const bf16x8*)(Abase + (size_t)m * 16 * DIM + k);
#pragma unroll
        for (int n = 0; n < 4; ++n)
            bw[n] = *(const bf16x8*)(Wbase + (size_t)n * 16 * DIM + k);
#pragma unroll
        for (int m = 0; m < 4; ++m)
#pragma unroll
            for (int n = 0; n < 4; ++n)
                acc[m][n] = __builtin_amdgcn_mfma_f32_16x16x32_bf16(af[m], bw[n], acc[m][n], 0, 0, 0);
    }
    const int cr = (lane >> 4) * 4;
#pragma unroll
    for (int m = 0; m < 4; ++m)
#pragma unroll
        for (int n = 0; n < 4; ++n)
#pragma unroll
            for (int r = 0; r < 4; ++r) {
                int row = bm * 128 + wm + m * 16 + cr + r;
                int col = bn * 128 + wn + n * 16 + lr;
                C[(size_t)row * GATES + col] = __float2bfloat16(acc[m][n][r]);
            }
}

// --------------------- sharded, leader-broadcast, fence-free barrier -----
// Per 64-block half: 8 arrival counters on separate 256B lines (<=8 adds
// each), leader (bid==0) sums them then publishes a monotonic go-tag on its
// own line; others poll the read-only go line with s_sleep pacing. Arrival
// RMWs never contend with polls. Release = s_waitcnt vmcnt(0) before the add
// (all coherent stores LLC-acked); consumers use coherent loads only.
static __device__ __forceinline__ void gbar(unsigned* barh, unsigned tgt, int bid) {
    __syncthreads();
    if (threadIdx.x == 0) {
        asm volatile("s_waitcnt vmcnt(0)" ::: "memory");
        __hip_atomic_fetch_add(barh + ((bid & 7) << 6), 1u,
                               __ATOMIC_RELAXED, __HIP_MEMORY_SCOPE_AGENT);
        if (bid == 0) {
            unsigned s;
            do {
                __builtin_amdgcn_s_sleep(1);
                s = 0;
#pragma unroll
                for (int i = 0; i < 8; ++i)
                    s += __hip_atomic_load(barh + (i << 6),
                                           __ATOMIC_RELAXED, __HIP_MEMORY_SCOPE_AGENT);
            } while (s < tgt);
            __hip_atomic_store(barh + 512, tgt,
                               __ATOMIC_RELAXED, __HIP_MEMORY_SCOPE_AGENT);
        } else {
            while (__hip_atomic_load(barh + 512,
                                     __ATOMIC_RELAXED, __HIP_MEMORY_SCOPE_AGENT) < tgt)
                __builtin_amdgcn_s_sleep(2);
        }
    }
    __syncthreads();
}

static __device__ __forceinline__ void block_reduce2(float& s, float& s2,
                                                     float (*red)[4], int lane, int w) {
#pragma unroll
    for (int off = 32; off > 0; off >>= 1) {
        s  += __shfl_down(s, off, 64);
        s2 += __shfl_down(s2, off, 64);
    }
    if (lane == 0) { red[0][w] = s; red[1][w] = s2; }
    __syncthreads();
    s  = red[0][0] + red[0][1] + red[0][2] + red[0][3];
    s2 = red[1][0] + red[1][1] + red[1][2] + red[1][3];
    __syncthreads();
}

// -------------------------------------------------- persistent scan ------
// 128 blocks = 2 independent 64-block halves (half = mi = blockIdx&1).
// Half mi handles batches [mi*16, +16): phase 1 computes their gate tiles,
// phase 2 owners are the colg<16 blocks of the same half (owner of batch
// b = mi*16+colg). No data crosses halves, so each half barriers alone.
__global__ __launch_bounds__(256) void scan_kernel(
    const bf16* __restrict__ gx,        // [T][B][4096] bf16
    const bf16* __restrict__ Wh_b,      // [4096][1024] bf16 (L2-resident)
    const float* __restrict__ c0,
    const float* __restrict__ gn_g, const float* __restrict__ gn_b,
    const float* __restrict__ cn_g, const float* __restrict__ cn_b,
    bf16* __restrict__ h_b,             // [B][H] recurrent state (coherent)
    float* __restrict__ gates_pre,      // [B][4096] scratch (coherent)
    float* __restrict__ out,
    float* __restrict__ h_final,
    float* __restrict__ c_final,
    unsigned* __restrict__ bar) {

    const int tid  = threadIdx.x;
    const int lane = tid & 63;
    const int w    = tid >> 6;
    const int mi   = blockIdx.x & 1;     // half / batch-half: rows mi*16..+16
    const int colg = blockIdx.x >> 1;    // 0..63: gate cols [colg*64, +64)
    const int ni   = colg * 4 + w;       // this wave's 16-col tile
    const int lr   = lane & 15;
    const int ko   = (lane >> 4) * 8;
    const int cr   = (lane >> 4) * 4;
    const int gcol = ni * 16 + lr;
    const int brow = mi * 16 + cr;

    unsigned* barh = bar + mi * 1024;    // this half's barrier state

    __shared__ __align__(16) char hsm[16 * 2048];   // 16 rows x 1024 bf16, XOR-swizzled
    __shared__ float red[2][4];

    const bf16* wbase = Wh_b + (size_t)(ni * 16 + lr) * HID + ko;   // normal cached
    const int arow = lr * 2048;
    const int axor = (lr & 7) << 4;

    // phase-2 ownership: owner of batch b = mi*16+colg is this block iff colg<16
    const bool owner = (colg < 16);
    const int b = mi * 16 + colg;
    float creg[4];
    if (owner) {
#pragma unroll
        for (int q = 0; q < 4; ++q) creg[q] = c0[b * HID + 4 * tid + q];
    }
    unsigned tgt = 0;

    for (int t = 0; t < T_STEPS; ++t) {
        // ---- gx prefetch (non-temporal: don't evict Wh from L2); latency
        //      hides under the h-stage coherent loads below ----
        u16 gxu[4];
        {
            const u16* gxp = (const u16*)(gx + ((size_t)t * BATCH + brow) * GATES + gcol);
#pragma unroll
            for (int r = 0; r < 4; ++r)
                gxu[r] = __builtin_nontemporal_load(gxp + (size_t)r * GATES);
        }

        // ---- phase 1a: stage h rows [mi*16, +16) into swizzled LDS ----
        {
            const u64* hsrc = (const u64*)(h_b + (size_t)mi * 16 * HID);
#pragma unroll
            for (int u = 0; u < 16; ++u) {
                int i = u * 256 + tid;           // u64 granule 0..4095
                int row = i >> 8;                // 256 u64 per row
                int off8 = (i & 255) << 3;       // byte 0..2047 within row
                u64 v = ldc_u64(hsrc + i);
                *(u64*)(hsm + row * 2048 + (off8 ^ ((row & 7) << 4))) = v;
            }
        }
        __syncthreads();

        // ---- phase 1b: 16x16 tile of h @ Wh^T, add gx, publish gates ----
        {
            f32x4 acc = {0.f, 0.f, 0.f, 0.f};
#pragma unroll 8
            for (int kk = 0; kk < 32; ++kk) {
                bf16x8 a = *(const bf16x8*)(hsm + arow + ((kk * 64 + ko * 2) ^ axor));
                bf16x8 bb = *(const bf16x8*)(wbase + kk * 32);
                acc = __builtin_amdgcn_mfma_f32_16x16x32_bf16(a, bb, acc, 0, 0, 0);
            }
            float* gp = gates_pre + (size_t)brow * GATES + gcol;
#pragma unroll
            for (int r = 0; r < 4; ++r) {
                union { u16 u; bf16 h; } cv; cv.u = gxu[r];
                stc_f32(gp + (size_t)r * GATES, acc[r] + __bfloat162float(cv.h));
            }
        }
        tgt += HBLK;
        gbar(barh, tgt, colg);

        // ---- phase 2: batch-owner blocks do LN + LSTM cell ----
        if (owner) {
            const u64* grow = (const u64*)(gates_pre + (size_t)b * GATES);
            float g[4][4];
            float s = 0.f, s2 = 0.f;
#pragma unroll
            for (int gq = 0; gq < 4; ++gq) {
                union { u64 u; float f[2]; } v0, v1;
                v0.u = ldc_u64(grow + gq * 512 + 2 * tid);
                v1.u = ldc_u64(grow + gq * 512 + 2 * tid + 1);
                g[gq][0] = v0.f[0]; g[gq][1] = v0.f[1];
                g[gq][2] = v1.f[0]; g[gq][3] = v1.f[1];
#pragma unroll
                for (int q = 0; q < 4; ++q) { s += g[gq][q]; s2 += g[gq][q] * g[gq][q]; }
            }
            block_reduce2(s, s2, red, lane, w);
            const float mu   = s * (1.0f / GATES);
            const float rstd = rsqrtf(s2 * (1.0f / GATES) - mu * mu + 1e-5f);

            float ov[4], cn_[4];
            float cs = 0.f, cs2 = 0.f;
#pragma unroll
            for (int q = 0; q < 4; ++q) {
                int j = 4 * tid + q;
                float iv = sigmf(   (g[0][q] - mu) * rstd * gn_g[j]            + gn_b[j]);
                float fv = sigmf(   (g[1][q] - mu) * rstd * gn_g[HID + j]      + gn_b[HID + j]);
                float gv = tanhfast((g[2][q] - mu) * rstd * gn_g[2 * HID + j]  + gn_b[2 * HID + j]);
                ov[q] =             (g[3][q] - mu) * rstd * gn_g[3 * HID + j]  + gn_b[3 * HID + j];
                float cnew = fv * creg[q] + iv * gv;
                cn_[q] = cnew;
                cs += cnew; cs2 += cnew * cnew;
            }
            block_reduce2(cs, cs2, red, lane, w);
            const float mu2   = cs * (1.0f / HID);
            const float rstd2 = rsqrtf(cs2 * (1.0f / HID) - mu2 * mu2 + 1e-5f);

            float* orow = out + ((size_t)t * BATCH + b) * HID + 4 * tid;
            union { u64 u; unsigned short h[4]; } hpack;
#pragma unroll
            for (int q = 0; q < 4; ++q) {
                int j = 4 * tid + q;
                float cn = (cn_[q] - mu2) * rstd2 * cn_g[j] + cn_b[j];
                creg[q] = cn;
                float hv = sigmf(ov[q]) * tanhfast(cn);
                __builtin_nontemporal_store(hv, orow + q);     // don't evict Wh
                hpack.h[q] = __bfloat16_as_ushort(__float2bfloat16(hv));
                if (t == T_STEPS - 1) {
                    h_final[b * HID + j] = hv;
                    c_final[b * HID + j] = cn;
                }
            }
            stc_u64((u64*)(h_b + (size_t)b * HID + 4 * tid), hpack.u);  // coherent publish
        }
        tgt += HBLK;
        gbar(barh, tgt, colg);
    }
}

// ----------------------------------------------------------- launcher ----
extern "C" void kernel_launch(void* const* d_in, const int* in_sizes, int n_in,
                              void* d_out, int out_size, void* d_ws, size_t ws_size,
                              hipStream_t stream) {
    const float* input = (const float*)d_in[0];
    const float* h0    = (const float*)d_in[1];
    const float* c0    = (const float*)d_in[2];
    const float* Wx    = (const float*)d_in[3];
    const float* Wh    = (const float*)d_in[4];
    const float* gn_g  = (const float*)d_in[5];
    const float* gn_b  = (const float*)d_in[6];
    const float* cn_g  = (const float*)d_in[7];
    const float* cn_b  = (const float*)d_in[8];

    char* ws = (char*)d_ws;
    size_t off = 0;
    auto alloc = [&](size_t bytes) -> char* {
        char* p = ws + off;
        off += (bytes + 255) & ~(size_t)255;
        return p;
    };
    bf16*     input_b   = (bf16*)    alloc((size_t)T_STEPS * BATCH * DIM * 2);
    bf16*     Wx_b      = (bf16*)    alloc((size_t)GATES * DIM * 2);
    bf16*     Wh_b      = (bf16*)    alloc((size_t)GATES * DIM * 2);
    bf16*     gates_x   = (bf16*)    alloc((size_t)T_STEPS * BATCH * GATES * 2);
    float*    gates_pre = (float*)   alloc((size_t)BATCH * GATES * 4);
    bf16*     h_b       = (bf16*)    alloc((size_t)BATCH * HID * 2);
    unsigned* bar       = (unsigned*)alloc(8192);   // 2 halves x 1024 dwords

    float* outp    = (float*)d_out;
    float* h_final = outp + (size_t)T_STEPS * BATCH * HID;
    float* c_final = h_final + (size_t)BATCH * HID;

    hipLaunchKernelGGL(prep_kernel, dim3(2048), dim3(256), 0, stream,
                       input, Wx, Wh, h0, input_b, Wx_b, Wh_b, h_b, bar);

    hipLaunchKernelGGL(gemm_input, dim3(4096), dim3(256), 0, stream,
                       input_b, Wx_b, gates_x);

    hipLaunchKernelGGL(scan_kernel, dim3(NBLK), dim3(256), 0, stream,
                       gates_x, Wh_b, c0, gn_g, gn_b, cn_g, cn_b,
                       h_b, gates_pre, outp, h_final, c_final, bar);
}